// Round 5
// baseline (146.129 us; speedup 1.0000x reference)
//
#include <hip/hip_runtime.h>
#include <math.h>

#define N_NODES 50000
#define N_EDGES 800000
#define D_FEAT 64
#define XCHUNKS (N_NODES * D_FEAT / 8)          // 400000 x-convert chunks (8 elems each)
#define ROWS_PER_BLOCK 32                       // 4 waves * 8 row-groups
#define NBLK ((N_NODES + ROWS_PER_BLOCK - 1) / ROWS_PER_BLOCK)  // 1563

// ---- bf16 helpers (RNE) ----
__device__ __forceinline__ unsigned short f2bf(float f) {
    unsigned u = __float_as_uint(f);
    u += 0x7FFFu + ((u >> 16) & 1u);
    return (unsigned short)(u >> 16);
}
__device__ __forceinline__ unsigned pack2bf(float lo, float hi) {
    return (unsigned)f2bf(lo) | ((unsigned)f2bf(hi) << 16);
}

// Fast ELU: native v_exp_f32 (abs threshold 0.765 makes expm1 precision moot).
__device__ __forceinline__ float elu_f(float x) {
    return x > 0.f ? x : (__expf(x) - 1.f);
}

// Prep: row_ptr lower-bound; pack edges as (col*128 byte-off, val bits);
// convert x (f32) -> xbf (bf16).
__global__ __launch_bounds__(256) void prep_kernel(const int* __restrict__ rows,
                                                   const int* __restrict__ cols,
                                                   const float* __restrict__ vals,
                                                   const float* __restrict__ x,
                                                   int* __restrict__ row_ptr,
                                                   int2* __restrict__ pairs,
                                                   unsigned short* __restrict__ xbf,
                                                   int do_pack) {
    const int i = blockIdx.x * blockDim.x + threadIdx.x;
    if (i <= N_NODES) {
        int lo = 0, hi = N_EDGES;
        while (lo < hi) {
            int mid = (lo + hi) >> 1;
            if (rows[mid] < i) lo = mid + 1; else hi = mid;
        }
        row_ptr[i] = lo;
    }
    if (do_pack && i < N_EDGES) {
        pairs[i] = make_int2(cols[i] << 7, __float_as_int(vals[i]));
    }
    if (i < XCHUNKS) {
        const float4 f0 = *reinterpret_cast<const float4*>(x + (size_t)i * 8);
        const float4 f1 = *reinterpret_cast<const float4*>(x + (size_t)i * 8 + 4);
        uint4 w;
        w.x = pack2bf(f0.x, f0.y);
        w.y = pack2bf(f0.z, f0.w);
        w.z = pack2bf(f1.x, f1.y);
        w.w = pack2bf(f1.z, f1.w);
        *reinterpret_cast<uint4*>(xbf + (size_t)i * 8) = w;
    }
}

// One 4-edge step for one row-group (8 lanes, 8 bf16 features per lane).
template <bool PACKED, bool MASKED>
__device__ __forceinline__ void edge_step4(const char* __restrict__ hb,
                                           const int2* __restrict__ pairs,
                                           const int* __restrict__ cols,
                                           const float* __restrict__ vals,
                                           int e, int e1, int boff, float acc[8]) {
    int off[4]; float v[4];
    #pragma unroll
    for (int k = 0; k < 4; ++k) {
        const int t = e + k;
        const int idx = MASKED ? (t < e1 ? t : e1 - 1) : t;
        if constexpr (PACKED) {
            // nontemporal: edge stream is read once; don't evict the h-table from L2
            const unsigned long long pw =
                __builtin_nontemporal_load((const unsigned long long*)pairs + idx);
            off[k] = (int)(unsigned)(pw & 0xFFFFFFFFull);
            v[k]   = __uint_as_float((unsigned)(pw >> 32));
        } else {
            off[k] = __builtin_nontemporal_load(cols + idx) << 7;
            v[k]   = __builtin_nontemporal_load(vals + idx);
        }
        if (MASKED) v[k] = (t < e1) ? v[k] : 0.f;
    }
    uint4 gw[4];
    #pragma unroll
    for (int k = 0; k < 4; ++k)
        gw[k] = *reinterpret_cast<const uint4*>(hb + (unsigned)(off[k] + boff));
    #pragma unroll
    for (int k = 0; k < 4; ++k) {
        const unsigned w0 = gw[k].x, w1 = gw[k].y, w2 = gw[k].z, w3 = gw[k].w;
        const float vk = v[k];
        acc[0] = fmaf(vk, __uint_as_float(w0 << 16),          acc[0]);
        acc[1] = fmaf(vk, __uint_as_float(w0 & 0xFFFF0000u),  acc[1]);
        acc[2] = fmaf(vk, __uint_as_float(w1 << 16),          acc[2]);
        acc[3] = fmaf(vk, __uint_as_float(w1 & 0xFFFF0000u),  acc[3]);
        acc[4] = fmaf(vk, __uint_as_float(w2 << 16),          acc[4]);
        acc[5] = fmaf(vk, __uint_as_float(w2 & 0xFFFF0000u),  acc[5]);
        acc[6] = fmaf(vk, __uint_as_float(w3 << 16),          acc[6]);
        acc[7] = fmaf(vk, __uint_as_float(w3 & 0xFFFF0000u),  acc[7]);
    }
}

// SpMM layer over bf16 h: 4 waves/block, 8 row-groups/wave (8 lanes per row,
// 8 bf16 features per lane = 16B gather; one gather instr serves 8 edges).
// !FUSE: h_out is bf16 [N_NODES][64].  FUSE: h_out is f32 out = y @ W^T + b.
template <bool FUSE, bool PACKED>
__global__ __launch_bounds__(256) void gcn_layer(
    const unsigned short* __restrict__ h_in,  // bf16 [N_NODES][64]
    const int2*  __restrict__ pairs,
    const int*   __restrict__ cols,
    const float* __restrict__ vals,
    const int*   __restrict__ row_ptr,
    const float* __restrict__ scalar_p,
    const float* __restrict__ W,        // [64,64] (FUSE only)
    const float* __restrict__ bvec,     // [64]    (FUSE only)
    void*        __restrict__ h_out)
{
    __shared__ float Wlds[FUSE ? 64 * 65 : 1];   // stride 65: conflict-free
    __shared__ float ylds[FUSE ? 4 * 8 * 68 : 1];

    const int lane = threadIdx.x & 63;
    const int wave = threadIdx.x >> 6;
    const int g    = lane >> 3;          // row-group 0..7
    const int l8   = lane & 7;           // 16B feature chunk
    const int boff = l8 * 16;

    if constexpr (FUSE) {
        for (int i = threadIdx.x; i < 64 * 64; i += 256)
            Wlds[(i >> 6) * 65 + (i & 63)] = W[i];
        __syncthreads();
    }

    const int row = blockIdx.x * ROWS_PER_BLOCK + wave * 8 + g;
    const float s = scalar_p[0];
    int e0 = 0, e1 = 0;
    if (row < N_NODES) { e0 = row_ptr[row]; e1 = row_ptr[row + 1]; }
    const char* hb = (const char*)h_in;

    float acc[8] = {0.f, 0.f, 0.f, 0.f, 0.f, 0.f, 0.f, 0.f};

    int e = e0;
    for (; e + 4 <= e1; e += 4)
        edge_step4<PACKED, false>(hb, pairs, cols, vals, e, e1, boff, acc);
    if (e < e1)
        edge_step4<PACKED, true>(hb, pairs, cols, vals, e, e1, boff, acc);

    #pragma unroll
    for (int f = 0; f < 8; ++f) acc[f] = elu_f(acc[f] * s);

    if constexpr (!FUSE) {
        if (row < N_NODES) {
            uint4 wv;
            wv.x = pack2bf(acc[0], acc[1]);
            wv.y = pack2bf(acc[2], acc[3]);
            wv.z = pack2bf(acc[4], acc[5]);
            wv.w = pack2bf(acc[6], acc[7]);
            *reinterpret_cast<uint4*>((char*)h_out + (size_t)row * 128 + boff) = wv;
        }
    } else {
        float* yw = ylds + wave * (8 * 68);
        float* yr = yw + g * 68 + l8 * 8;
        *reinterpret_cast<float4*>(yr)     = make_float4(acc[0], acc[1], acc[2], acc[3]);
        *reinterpret_cast<float4*>(yr + 4) = make_float4(acc[4], acc[5], acc[6], acc[7]);
        asm volatile("s_waitcnt lgkmcnt(0)" ::: "memory");  // same-wave ds ordering

        const int j = lane;
        const float bj = bvec[j];
        float o[8];
        #pragma unroll
        for (int r = 0; r < 8; ++r) o[r] = bj;
        #pragma unroll
        for (int d0 = 0; d0 < 16; ++d0) {
            const float* wr = Wlds + j * 65 + d0 * 4;
            const float w0 = wr[0], w1 = wr[1], w2 = wr[2], w3 = wr[3];
            #pragma unroll
            for (int r = 0; r < 8; ++r) {
                const float4 y = *reinterpret_cast<const float4*>(yw + r * 68 + d0 * 4);
                o[r] = fmaf(y.x, w0, o[r]); o[r] = fmaf(y.y, w1, o[r]);
                o[r] = fmaf(y.z, w2, o[r]); o[r] = fmaf(y.w, w3, o[r]);
            }
        }
        const int rbase = blockIdx.x * ROWS_PER_BLOCK + wave * 8;
        float* outp = (float*)h_out;
        #pragma unroll
        for (int r = 0; r < 8; ++r)
            if (rbase + r < N_NODES)
                outp[(size_t)(rbase + r) * D_FEAT + j] = o[r];
    }
}

extern "C" void kernel_launch(void* const* d_in, const int* in_sizes, int n_in,
                              void* d_out, int out_size, void* d_ws, size_t ws_size,
                              hipStream_t stream) {
    const float* x       = (const float*)d_in[0];
    const int*   rows    = (const int*)  d_in[1];
    const int*   cols    = (const int*)  d_in[2];
    const float* vals    = (const float*)d_in[3];
    const float* scalars = (const float*)d_in[4];
    const float* W       = (const float*)d_in[5];
    const float* b       = (const float*)d_in[6];
    float* out = (float*)d_out;

    // ws layout: row_ptr | xbf (bf16) | h1 (bf16) | (optional) packed pairs
    const size_t rp_b = (sizeof(int) * (N_NODES + 1) + 255) & ~size_t(255);
    const size_t xb_b = ((size_t)N_NODES * D_FEAT * 2 + 255) & ~size_t(255);
    const size_t pr_b = sizeof(int2) * (size_t)N_EDGES;

    int*            row_ptr = (int*)d_ws;
    unsigned short* xbf     = (unsigned short*)((char*)d_ws + rp_b);
    unsigned short* h1      = (unsigned short*)((char*)d_ws + rp_b + xb_b);
    const bool packed = ws_size >= rp_b + 2 * xb_b + pr_b;
    int2* pairs = packed ? (int2*)((char*)d_ws + rp_b + 2 * xb_b) : nullptr;

    prep_kernel<<<(N_EDGES + 255) / 256, 256, 0, stream>>>(
        rows, cols, vals, x, row_ptr, pairs, xbf, packed ? 1 : 0);

    if (packed) {
        gcn_layer<false, true><<<NBLK, 256, 0, stream>>>(
            xbf, pairs, cols, vals, row_ptr, scalars + 0, nullptr, nullptr, h1);
        gcn_layer<true, true><<<NBLK, 256, 0, stream>>>(
            h1, pairs, cols, vals, row_ptr, scalars + 1, W, b, out);
    } else {
        gcn_layer<false, false><<<NBLK, 256, 0, stream>>>(
            xbf, nullptr, cols, vals, row_ptr, scalars + 0, nullptr, nullptr, h1);
        gcn_layer<true, false><<<NBLK, 256, 0, stream>>>(
            h1, nullptr, cols, vals, row_ptr, scalars + 1, W, b, out);
    }
}

// Round 6
// 58.630 us; speedup vs baseline: 2.4924x; 2.4924x over previous
//
#include <hip/hip_runtime.h>
#include <math.h>

#define N_NODES 50000
#define N_EDGES 800000
#define D_FEAT 64
#define XCHUNKS (N_NODES * D_FEAT / 8)   // 400000 x->bf16 chunks (8 elems each)
#define NBLK 3125                        // 16 rows/block * 3125 = 50000 exactly

// ---- bf16 helpers (RNE) ----
__device__ __forceinline__ unsigned short f2bf(float f) {
    unsigned u = __float_as_uint(f);
    u += 0x7FFFu + ((u >> 16) & 1u);
    return (unsigned short)(u >> 16);
}
__device__ __forceinline__ unsigned pack2bf(float lo, float hi) {
    return (unsigned)f2bf(lo) | ((unsigned)f2bf(hi) << 16);
}

// Fast ELU: native v_exp_f32 (abs threshold 0.765 makes expm1 precision moot).
__device__ __forceinline__ float elu_f(float x) {
    return x > 0.f ? x : (__expf(x) - 1.f);
}

// Prep: row_ptr lower-bound; pack edges as (col*128 byte-off, val bits);
// convert x (f32) -> bf16 table.
__global__ __launch_bounds__(256) void prep_kernel(const int* __restrict__ rows,
                                                   const int* __restrict__ cols,
                                                   const float* __restrict__ vals,
                                                   const float* __restrict__ x,
                                                   int* __restrict__ row_ptr,
                                                   int2* __restrict__ pairs,
                                                   unsigned short* __restrict__ xbf,
                                                   int do_pack) {
    const int i = blockIdx.x * blockDim.x + threadIdx.x;
    if (i <= N_NODES) {
        int lo = 0, hi = N_EDGES;
        while (lo < hi) {
            int mid = (lo + hi) >> 1;
            if (rows[mid] < i) lo = mid + 1; else hi = mid;
        }
        row_ptr[i] = lo;
    }
    if (do_pack && i < N_EDGES) {
        pairs[i] = make_int2(cols[i] << 7, __float_as_int(vals[i]));
    }
    if (i < XCHUNKS) {
        const float4 f0 = *reinterpret_cast<const float4*>(x + (size_t)i * 8);
        const float4 f1 = *reinterpret_cast<const float4*>(x + (size_t)i * 8 + 4);
        uint4 w;
        w.x = pack2bf(f0.x, f0.y);
        w.y = pack2bf(f0.z, f0.w);
        w.z = pack2bf(f1.x, f1.y);
        w.w = pack2bf(f1.z, f1.w);
        *reinterpret_cast<uint4*>(xbf + (size_t)i * 8) = w;
    }
}

// One 8-edge step for one row-group (16 lanes/row, 4 bf16 features per lane).
// Structure identical to the round-4 (32-VGPR, 68%-occ) version; only the
// gather width (uint2 vs float4) and the unpack differ.
template <bool PACKED, bool MASKED>
__device__ __forceinline__ void edge_step8(const char* __restrict__ hb,
                                           const int2* __restrict__ pairs,
                                           const int* __restrict__ cols,
                                           const float* __restrict__ vals,
                                           int e, int e1, int boff,
                                           float4& A, float4& B) {
    int off[8]; float v[8];
    #pragma unroll
    for (int k = 0; k < 8; ++k) {
        const int t = e + k;
        const int idx = MASKED ? (t < e1 ? t : e1 - 1) : t;
        if constexpr (PACKED) {
            const int2 p = pairs[idx];
            off[k] = p.x;
            v[k] = __int_as_float(p.y);
        } else {
            off[k] = cols[idx] << 7;
            v[k] = vals[idx];
        }
        if (MASKED) v[k] = (t < e1) ? v[k] : 0.f;
    }
    uint2 gg[8];
    #pragma unroll
    for (int k = 0; k < 8; ++k)
        gg[k] = *reinterpret_cast<const uint2*>(hb + (unsigned)(off[k] + boff));
    #pragma unroll
    for (int k = 0; k < 8; ++k) {
        float4& acc = (k & 1) ? B : A;
        const float vk = v[k];
        acc.x = fmaf(vk, __uint_as_float(gg[k].x << 16),         acc.x);
        acc.y = fmaf(vk, __uint_as_float(gg[k].x & 0xFFFF0000u), acc.y);
        acc.z = fmaf(vk, __uint_as_float(gg[k].y << 16),         acc.z);
        acc.w = fmaf(vk, __uint_as_float(gg[k].y & 0xFFFF0000u), acc.w);
    }
}

// SpMM layer over bf16 h: 4 waves/block, 4 row-groups/wave (16 lanes per row,
// 4 bf16 features per lane = 8B gather; 128B line per edge).
// !FUSE: h_out is bf16 [N_NODES][64].  FUSE: h_out is f32 out = y @ W^T + b.
template <bool FUSE, bool PACKED>
__global__ __launch_bounds__(256) void gcn_layer(
    const unsigned short* __restrict__ h_in,  // bf16 [N_NODES][64]
    const int2*  __restrict__ pairs,
    const int*   __restrict__ cols,
    const float* __restrict__ vals,
    const int*   __restrict__ row_ptr,
    const float* __restrict__ scalar_p,
    const float* __restrict__ W,        // [64,64] (FUSE only)
    const float* __restrict__ bvec,     // [64]    (FUSE only)
    void*        __restrict__ h_out)
{
    __shared__ float Wlds[FUSE ? 64 * 65 : 1];   // stride 65: 2-way (free) reads
    __shared__ float ylds[FUSE ? 4 * 4 * 68 : 1];// [wave][row][68 pad]

    const int lane = threadIdx.x & 63;
    const int wave = threadIdx.x >> 6;
    const int g    = lane >> 4;          // row-group 0..3
    const int f4   = lane & 15;          // 8B feature chunk index
    const int boff = f4 * 8;             // byte offset of this lane's chunk

    if constexpr (FUSE) {
        for (int i = threadIdx.x; i < 64 * 64; i += 256)
            Wlds[(i >> 6) * 65 + (i & 63)] = W[i];
        __syncthreads();
    }

    const int row = blockIdx.x * 16 + wave * 4 + g;
    const float s  = scalar_p[0];
    const int  e0  = row_ptr[row];
    const int  e1  = row_ptr[row + 1];
    const char* hb = (const char*)h_in;

    float4 A = make_float4(0.f, 0.f, 0.f, 0.f);
    float4 B = A;

    int e = e0;
    for (; e + 8 <= e1; e += 8)
        edge_step8<PACKED, false>(hb, pairs, cols, vals, e, e1, boff, A, B);
    if (e < e1)
        edge_step8<PACKED, true>(hb, pairs, cols, vals, e, e1, boff, A, B);

    float4 acc;
    acc.x = elu_f((A.x + B.x) * s);
    acc.y = elu_f((A.y + B.y) * s);
    acc.z = elu_f((A.z + B.z) * s);
    acc.w = elu_f((A.w + B.w) * s);

    if constexpr (!FUSE) {
        uint2 wv;
        wv.x = pack2bf(acc.x, acc.y);
        wv.y = pack2bf(acc.z, acc.w);
        *reinterpret_cast<uint2*>((char*)h_out + (size_t)row * 128 + boff) = wv;
    } else {
        float* yw = ylds + wave * (4 * 68);
        *reinterpret_cast<float4*>(yw + g * 68 + f4 * 4) = acc;
        asm volatile("s_waitcnt lgkmcnt(0)" ::: "memory");  // same-wave ds ordering

        const int j = lane;
        const float bj = bvec[j];
        float o0 = bj, o1 = bj, o2 = bj, o3 = bj;
        #pragma unroll
        for (int d0 = 0; d0 < 16; ++d0) {
            const float* wr = Wlds + j * 65 + d0 * 4;  // 2-way banked: free
            const float w0 = wr[0], w1 = wr[1], w2 = wr[2], w3 = wr[3];
            const float4 y0 = *reinterpret_cast<const float4*>(yw + 0 * 68 + d0 * 4);
            const float4 y1 = *reinterpret_cast<const float4*>(yw + 1 * 68 + d0 * 4);
            const float4 y2 = *reinterpret_cast<const float4*>(yw + 2 * 68 + d0 * 4);
            const float4 y3 = *reinterpret_cast<const float4*>(yw + 3 * 68 + d0 * 4);
            o0 = fmaf(y0.x, w0, o0); o0 = fmaf(y0.y, w1, o0);
            o0 = fmaf(y0.z, w2, o0); o0 = fmaf(y0.w, w3, o0);
            o1 = fmaf(y1.x, w0, o1); o1 = fmaf(y1.y, w1, o1);
            o1 = fmaf(y1.z, w2, o1); o1 = fmaf(y1.w, w3, o1);
            o2 = fmaf(y2.x, w0, o2); o2 = fmaf(y2.y, w1, o2);
            o2 = fmaf(y2.z, w2, o2); o2 = fmaf(y2.w, w3, o2);
            o3 = fmaf(y3.x, w0, o3); o3 = fmaf(y3.y, w1, o3);
            o3 = fmaf(y3.z, w2, o3); o3 = fmaf(y3.w, w3, o3);
        }
        const size_t rbase = (size_t)(blockIdx.x * 16 + wave * 4) * D_FEAT;
        float* outp = (float*)h_out;
        outp[rbase + 0 * D_FEAT + j] = o0;
        outp[rbase + 1 * D_FEAT + j] = o1;
        outp[rbase + 2 * D_FEAT + j] = o2;
        outp[rbase + 3 * D_FEAT + j] = o3;
    }
}

extern "C" void kernel_launch(void* const* d_in, const int* in_sizes, int n_in,
                              void* d_out, int out_size, void* d_ws, size_t ws_size,
                              hipStream_t stream) {
    const float* x       = (const float*)d_in[0];
    const int*   rows    = (const int*)  d_in[1];
    const int*   cols    = (const int*)  d_in[2];
    const float* vals    = (const float*)d_in[3];
    const float* scalars = (const float*)d_in[4];
    const float* W       = (const float*)d_in[5];
    const float* b       = (const float*)d_in[6];
    float* out = (float*)d_out;

    // ws layout: row_ptr | xbf (bf16) | h1 (bf16) | (optional) packed pairs
    const size_t rp_b = (sizeof(int) * (N_NODES + 1) + 255) & ~size_t(255);
    const size_t xb_b = ((size_t)N_NODES * D_FEAT * 2 + 255) & ~size_t(255);
    const size_t pr_b = sizeof(int2) * (size_t)N_EDGES;

    int*            row_ptr = (int*)d_ws;
    unsigned short* xbf     = (unsigned short*)((char*)d_ws + rp_b);
    unsigned short* h1      = (unsigned short*)((char*)d_ws + rp_b + xb_b);
    const bool packed = ws_size >= rp_b + 2 * xb_b + pr_b;
    int2* pairs = packed ? (int2*)((char*)d_ws + rp_b + 2 * xb_b) : nullptr;

    prep_kernel<<<(N_EDGES + 255) / 256, 256, 0, stream>>>(
        rows, cols, vals, x, row_ptr, pairs, xbf, packed ? 1 : 0);

    if (packed) {
        gcn_layer<false, true><<<NBLK, 256, 0, stream>>>(
            xbf, pairs, cols, vals, row_ptr, scalars + 0, nullptr, nullptr, h1);
        gcn_layer<true, true><<<NBLK, 256, 0, stream>>>(
            h1, pairs, cols, vals, row_ptr, scalars + 1, W, b, out);
    } else {
        gcn_layer<false, false><<<NBLK, 256, 0, stream>>>(
            xbf, nullptr, cols, vals, row_ptr, scalars + 0, nullptr, nullptr, h1);
        gcn_layer<true, false><<<NBLK, 256, 0, stream>>>(
            h1, nullptr, cols, vals, row_ptr, scalars + 1, W, b, out);
    }
}